// Round 15
// baseline (103.391 us; speedup 1.0000x reference)
//
#include <hip/hip_runtime.h>

typedef __attribute__((ext_vector_type(2))) __fp16 h2;
typedef __attribute__((ext_vector_type(4))) __fp16 h4;
typedef __attribute__((ext_vector_type(8))) __fp16 h8;
typedef __attribute__((ext_vector_type(4))) float f32x4;

#define LOG2E 1.44269504088896340736f

// ws layout (bytes) — identical to rounds 6-14 (verified passing)
#define WS_K    0ull            // 14*64 tiles * 8192 B
#define WS_MK   7340032ull      // 14*16 tiles * 8192 B
#define WS_VT   9175040ull      // 14*64 tiles * 512 B
#define WS_MVT  9633792ull      // 14*16 tiles * 512 B
#define WS_NEED 9748480ull

__device__ __forceinline__ h2 pkrtz(float a, float b) {
    return __builtin_bit_cast(h2, __builtin_amdgcn_cvt_pkrtz(a, b));
}

// ---------------- Precompute (verbatim rounds 6-14, verified) ----------------
__global__ __launch_bounds__(256) void kast_pre_kernel(
    const float* __restrict__ K, const float* __restrict__ V,
    const float* __restrict__ MK, const float* __restrict__ MV,
    char* __restrict__ ws)
{
    const int id = blockIdx.x * 256 + threadIdx.x;
    if (id < 573440) {
        const bool ismk = id >= 458752;
        const int lid = ismk ? id - 458752 : id;
        const int c = lid & 7;
        const int r = (lid >> 3) & 63;
        int kt, s;
        if (ismk) { kt = (lid >> 9) & 15; s = lid >> 13; }
        else      { kt = (lid >> 9) & 63; s = lid >> 15; }
        const int b = s / 7, t = s - b * 7;
        const float* src = ismk
            ? MK + (((size_t)(b * 7 + t) * 1024 + kt * 64 + r) * 64 + c * 8)
            : K  + (((size_t)(b * 8 + t) * 4096 + kt * 64 + r) * 64 + c * 8);
        const f32x4 xa = *(const f32x4*)src;
        const f32x4 xb = *(const f32x4*)(src + 4);
        const h2 q0 = pkrtz(xa[0], xa[1]), q1 = pkrtz(xa[2], xa[3]);
        const h2 q2 = pkrtz(xb[0], xb[1]), q3 = pkrtz(xb[2], xb[3]);
        const h8 out = {q0[0], q0[1], q1[0], q1[1], q2[0], q2[1], q3[0], q3[1]};
        __fp16* dst = (__fp16*)(ws + (ismk ? WS_MK : WS_K))
                    + (size_t)(ismk ? (s * 16 + kt) : (s * 64 + kt)) * 4096
                    + r * 64 + ((c ^ (r & 7)) * 8);
        *(h8*)dst = out;
    } else {
        const int vid = id - 573440;
        const bool ismv = vid >= 57344;
        const int lid = ismv ? vid - 57344 : vid;
        const int c = lid & 15;
        const int d = (lid >> 4) & 3;
        int kt, s;
        if (ismv) { kt = (lid >> 6) & 15; s = lid >> 10; }
        else      { kt = (lid >> 6) & 63; s = lid >> 12; }
        const int b = s / 7, t = s - b * 7;
        const float* src = ismv
            ? MV + (((size_t)(b * 7 + t) * 1024 + kt * 64 + c * 4) * 3)
            : V  + (((size_t)(b * 8 + t) * 4096 + kt * 64 + c * 4) * 3);
        float f0, f1, f2, f3;
        if (d == 3) { f0 = f1 = f2 = f3 = 1.0f; }
        else { f0 = src[d]; f1 = src[3 + d]; f2 = src[6 + d]; f3 = src[9 + d]; }
        const h2 pa = pkrtz(f0, f1), pb = pkrtz(f2, f3);
        const h4 out4 = {pa[0], pa[1], pb[0], pb[1]};
        __fp16* dst = (__fp16*)(ws + (ismv ? WS_MVT : WS_VT))
                    + (size_t)(ismv ? (s * 16 + kt) : (s * 64 + kt)) * 256
                    + d * 64 + (4 * ((c >> 2) ^ d) + (c & 3)) * 4;
        *(h4*)dst = out4;
    }
}

// ---- Main: r14 register-staged barrier-free flash + 2-stage modulo schedule.
// ---- QK(tile kt+1) MFMAs issue BEFORE softmax/PV(tile kt) so the matrix pipe
// ---- fills the softmax VALU shadow; fragments load 2 tiles ahead (L2-hot ws).
__global__ __launch_bounds__(256, 4) void kast_attn_kernel(
    const float* __restrict__ K,   // (2,8,4096,64) for Q
    const char* __restrict__ ws,
    float* __restrict__ OUT)       // (2,7,4096,3)
{
    __shared__ float mrg[4][32][5];   // [wave][q][{m,O0,O1,O2,l}]

    const int id = blockIdx.x;
    const int sw = (id & 7) * 224 + (id >> 3);   // XCD-chunked, bijective (1792%8==0)
    const int bt = sw >> 7;        // 0..13
    const int qblk = sw & 127;     // 0..127 (32 queries each)
    const int b = bt / 7, t = bt - b * 7;

    const int tid = threadIdx.x;
    const int lane = tid & 63;
    const int w = tid >> 6;        // wave 0..3 = key-quarter
    const int col = lane & 15;
    const int g = lane >> 4;       // k-chunk group
    const int cs = col & 7;        // swizzle key (row&7 == col&7)
    const int d3 = col & 3;        // V^T row

    // per-lane constant K-fragment byte offsets within a 4KB 32-key tile
    const int a00 = col * 128 + ((g ^ cs) * 16);            // ch0 nt0 (+2048 -> nt1)
    const int a10 = col * 128 + (((4 + g) ^ cs) * 16);      // ch1 nt0 (+2048 -> nt1)
    // per-lane constant V offsets within a 512B 64-key V-tile (after +d3*128)
    const int ov0 = (4 * (0 ^ d3) + g) * 8;   // even tile, nt0
    const int ov1 = (4 * (1 ^ d3) + g) * 8;   // even tile, nt1
    const int ov2 = (4 * (2 ^ d3) + g) * 8;   // odd tile, nt0
    const int ov3 = (4 * (3 ^ d3) + g) * 8;   // odd tile, nt1

    // ---- Q fragments (B operand), 2 M-tiles, scaled by log2(e) ----
    h8 aq00, aq01, aq10, aq11;     // aq[mt][ch]
    {
        const float* qp0 = K + (((size_t)b * 8 + (t + 1)) * 4096
                          + (size_t)(qblk * 32 + col)) * 64;
        const float* qp1 = qp0 + 16 * 64;
#pragma unroll
        for (int mt = 0; mt < 2; ++mt) {
            const float* qp = mt ? qp1 : qp0;
#pragma unroll
            for (int ch = 0; ch < 2; ++ch) {
                const int cc = ch * 32 + g * 8;
                const f32x4 xa = *(const f32x4*)&qp[cc];
                const f32x4 xb = *(const f32x4*)&qp[cc + 4];
                const h2 p0 = pkrtz(xa[0] * LOG2E, xa[1] * LOG2E);
                const h2 p1 = pkrtz(xa[2] * LOG2E, xa[3] * LOG2E);
                const h2 p2 = pkrtz(xb[0] * LOG2E, xb[1] * LOG2E);
                const h2 p3 = pkrtz(xb[2] * LOG2E, xb[3] * LOG2E);
                const h8 f = {p0[0], p0[1], p1[0], p1[1], p2[0], p2[1], p3[0], p3[1]};
                if (mt == 0 && ch == 0) aq00 = f;
                else if (mt == 0)       aq01 = f;
                else if (ch == 0)       aq10 = f;
                else                    aq11 = f;
            }
        }
    }

    float oa0 = 0.f, oa1 = 0.f, oa2 = 0.f;

#pragma unroll
    for (int phase = 0; phase < 2; ++phase) {
        const int n = phase ? 8 : 32;                 // 32-key tiles per quarter
        const float wgt = phase ? 0.2f : 0.8f;
        const char* kbase = phase
            ? ws + WS_MK  + (size_t)bt * 131072 + (size_t)w * 32768
            : ws + WS_K   + (size_t)bt * 524288 + (size_t)w * 131072;
        const char* vbase = (phase
            ? ws + WS_MVT + (size_t)bt * 8192  + (size_t)w * 2048
            : ws + WS_VT  + (size_t)bt * 32768 + (size_t)w * 8192) + d3 * 128;

        float mrun0 = -1e30f, mrun1 = -1e30f;
        f32x4 O0 = (f32x4){0.f,0.f,0.f,0.f}, O1 = (f32x4){0.f,0.f,0.f,0.f};

        h8 f0_00, f0_01, f0_10, f0_11;   // fragment set F0
        h8 f1_00, f1_01, f1_10, f1_11;   // fragment set F1
        h4 vA0, vA1, vB0, vB1;
        f32x4 cA00, cA01, cA10, cA11;    // acc set A
        f32x4 cB00, cB01, cB10, cB11;    // acc set B

#define LOADF0(TKT) { const char* tb = kbase + (size_t)(TKT) * 4096;              \
            f0_00 = *(const h8*)(tb + a00); f0_01 = *(const h8*)(tb + a00 + 2048);\
            f0_10 = *(const h8*)(tb + a10); f0_11 = *(const h8*)(tb + a10 + 2048); }
#define LOADF1(TKT) { const char* tb = kbase + (size_t)(TKT) * 4096;              \
            f1_00 = *(const h8*)(tb + a00); f1_01 = *(const h8*)(tb + a00 + 2048);\
            f1_10 = *(const h8*)(tb + a10); f1_11 = *(const h8*)(tb + a10 + 2048); }

#define QK(F00, F01, F10, F11, C00, C01, C10, C11)                                \
        {                                                                         \
            C00 = (f32x4){0.f,0.f,0.f,0.f}; C01 = C00; C10 = C00; C11 = C00;      \
            __builtin_amdgcn_s_setprio(1);                                        \
            C00 = __builtin_amdgcn_mfma_f32_16x16x32_f16(F00, aq00, C00, 0,0,0);  \
            C01 = __builtin_amdgcn_mfma_f32_16x16x32_f16(F01, aq00, C01, 0,0,0);  \
            C10 = __builtin_amdgcn_mfma_f32_16x16x32_f16(F00, aq10, C10, 0,0,0);  \
            C11 = __builtin_amdgcn_mfma_f32_16x16x32_f16(F01, aq10, C11, 0,0,0);  \
            C00 = __builtin_amdgcn_mfma_f32_16x16x32_f16(F10, aq01, C00, 0,0,0);  \
            C01 = __builtin_amdgcn_mfma_f32_16x16x32_f16(F11, aq01, C01, 0,0,0);  \
            C10 = __builtin_amdgcn_mfma_f32_16x16x32_f16(F10, aq11, C10, 0,0,0);  \
            C11 = __builtin_amdgcn_mfma_f32_16x16x32_f16(F11, aq11, C11, 0,0,0);  \
            __builtin_amdgcn_s_setprio(0);                                        \
        }

#define SMPV(C00, C01, C10, C11, V0, V1)                                          \
        {                                                                         \
            float tm0 = fmaxf(fmaxf(fmaxf(C00[0], C00[1]), fmaxf(C00[2], C00[3])),\
                              fmaxf(fmaxf(C01[0], C01[1]), fmaxf(C01[2], C01[3])));\
            float tm1 = fmaxf(fmaxf(fmaxf(C10[0], C10[1]), fmaxf(C10[2], C10[3])),\
                              fmaxf(fmaxf(C11[0], C11[1]), fmaxf(C11[2], C11[3])));\
            float s0 = __shfl_xor(tm0, 16), s1 = __shfl_xor(tm1, 16);             \
            tm0 = fmaxf(tm0, s0); tm1 = fmaxf(tm1, s1);                           \
            s0 = __shfl_xor(tm0, 32); s1 = __shfl_xor(tm1, 32);                   \
            tm0 = fmaxf(tm0, s0); tm1 = fmaxf(tm1, s1);                           \
            const float m0 = fmaxf(mrun0, tm0), m1 = fmaxf(mrun1, tm1);           \
            const float r0 = __builtin_amdgcn_exp2f(mrun0 - m0);                  \
            const float r1 = __builtin_amdgcn_exp2f(mrun1 - m1);                  \
            O0 *= r0; O1 *= r1; mrun0 = m0; mrun1 = m1;                           \
            {                                                                     \
                const float e0 = __builtin_amdgcn_exp2f(C00[0] - mrun0);          \
                const float e1 = __builtin_amdgcn_exp2f(C00[1] - mrun0);          \
                const float e2 = __builtin_amdgcn_exp2f(C00[2] - mrun0);          \
                const float e3 = __builtin_amdgcn_exp2f(C00[3] - mrun0);          \
                const h2 pa = pkrtz(e0, e1), pb = pkrtz(e2, e3);                  \
                const h4 pf = (h4){pa[0], pa[1], pb[0], pb[1]};                   \
                O0 = __builtin_amdgcn_mfma_f32_16x16x16f16(V0, pf, O0, 0, 0, 0);  \
            }                                                                     \
            {                                                                     \
                const float e0 = __builtin_amdgcn_exp2f(C01[0] - mrun0);          \
                const float e1 = __builtin_amdgcn_exp2f(C01[1] - mrun0);          \
                const float e2 = __builtin_amdgcn_exp2f(C01[2] - mrun0);          \
                const float e3 = __builtin_amdgcn_exp2f(C01[3] - mrun0);          \
                const h2 pa = pkrtz(e0, e1), pb = pkrtz(e2, e3);                  \
                const h4 pf = (h4){pa[0], pa[1], pb[0], pb[1]};                   \
                O0 = __builtin_amdgcn_mfma_f32_16x16x16f16(V1, pf, O0, 0, 0, 0);  \
            }                                                                     \
            {                                                                     \
                const float e0 = __builtin_amdgcn_exp2f(C10[0] - mrun1);          \
                const float e1 = __builtin_amdgcn_exp2f(C10[1] - mrun1);          \
                const float e2 = __builtin_amdgcn_exp2f(C10[2] - mrun1);          \
                const float e3 = __builtin_amdgcn_exp2f(C10[3] - mrun1);          \
                const h2 pa = pkrtz(e0, e1), pb = pkrtz(e2, e3);                  \
                const h4 pf = (h4){pa[0], pa[1], pb[0], pb[1]};                   \
                O1 = __builtin_amdgcn_mfma_f32_16x16x16f16(V0, pf, O1, 0, 0, 0);  \
            }                                                                     \
            {                                                                     \
                const float e0 = __builtin_amdgcn_exp2f(C11[0] - mrun1);          \
                const float e1 = __builtin_amdgcn_exp2f(C11[1] - mrun1);          \
                const float e2 = __builtin_amdgcn_exp2f(C11[2] - mrun1);          \
                const float e3 = __builtin_amdgcn_exp2f(C11[3] - mrun1);          \
                const h2 pa = pkrtz(e0, e1), pb = pkrtz(e2, e3);                  \
                const h4 pf = (h4){pa[0], pa[1], pb[0], pb[1]};                   \
                O1 = __builtin_amdgcn_mfma_f32_16x16x16f16(V1, pf, O1, 0, 0, 0);  \
            }                                                                     \
        }

        // ---- prologue: F0<-t0, F1<-t1, V(t0),V(t1); accA = QK(t0) ----
        LOADF0(0);
        LOADF1(1);
        vA0 = *(const h4*)(vbase + ov0); vA1 = *(const h4*)(vbase + ov1);
        vB0 = *(const h4*)(vbase + ov2); vB1 = *(const h4*)(vbase + ov3);
        QK(f0_00, f0_01, f0_10, f0_11, cA00, cA01, cA10, cA11);

        for (int kt = 0; kt < n; kt += 2) {
            const bool more = (kt + 2) < n;
            if (more) LOADF0(kt + 2);                     // F0 <- t(kt+2)
            QK(f1_00, f1_01, f1_10, f1_11, cB00, cB01, cB10, cB11);   // accB = t(kt+1)
            SMPV(cA00, cA01, cA10, cA11, vA0, vA1);       // tile kt (overlaps accB MFMAs)
            if (more) {
                LOADF1(kt + 3);                           // F1 <- t(kt+3)
                const char* vt = vbase + (size_t)((kt + 2) >> 1) * 512;
                vA0 = *(const h4*)(vt + ov0); vA1 = *(const h4*)(vt + ov1);
                QK(f0_00, f0_01, f0_10, f0_11, cA00, cA01, cA10, cA11);  // accA = t(kt+2)
            }
            SMPV(cB00, cB01, cB10, cB11, vB0, vB1);       // tile kt+1 (overlaps accA MFMAs)
            if (more) {
                const char* vt = vbase + (size_t)((kt + 2) >> 1) * 512;
                vB0 = *(const h4*)(vt + ov2); vB1 = *(const h4*)(vt + ov3);
            }
        }
#undef LOADF0
#undef LOADF1
#undef QK
#undef SMPV

        // ---- partials to LDS; exact 4-way flash merge (2 barriers/phase) ----
        if (g == 0) {
            float* m5a = &mrg[w][col][0];
            m5a[0] = mrun0;
            m5a[1] = O0[0]; m5a[2] = O0[1]; m5a[3] = O0[2]; m5a[4] = O0[3];
            float* m5b = &mrg[w][16 + col][0];
            m5b[0] = mrun1;
            m5b[1] = O1[0]; m5b[2] = O1[1]; m5b[3] = O1[2]; m5b[4] = O1[3];
        }
        __syncthreads();
        if (tid < 32) {
            float m = -1e30f;
#pragma unroll
            for (int q4 = 0; q4 < 4; ++q4) m = fmaxf(m, mrg[q4][tid][0]);
            float l = 0.f, r0 = 0.f, r1 = 0.f, r2 = 0.f;
#pragma unroll
            for (int q4 = 0; q4 < 4; ++q4) {
                const float* m5 = &mrg[q4][tid][0];
                const float e = __builtin_amdgcn_exp2f(m5[0] - m);
                r0 += m5[1] * e; r1 += m5[2] * e; r2 += m5[3] * e;
                l  += m5[4] * e;
            }
            const float inv = wgt / l;
            oa0 += r0 * inv; oa1 += r1 * inv; oa2 += r2 * inv;
        }
        __syncthreads();   // mrg free before next phase's partial writes
    }

    if (tid < 32) {
        const int q = qblk * 32 + tid;
        float* op = OUT + (((size_t)b * 7 + t) * 4096 + (size_t)q) * 3;
        op[0] = oa0; op[1] = oa1; op[2] = oa2;
    }
}

// ---------------- Fallback (round-4 kernel, known-good) if ws too small ----------------
__global__ __launch_bounds__(256) void kast_attn_fb(
    const float* __restrict__ K, const float* __restrict__ V,
    const float* __restrict__ MK, const float* __restrict__ MV,
    float* __restrict__ OUT)
{
    __shared__ alignas(16) __fp16 sK[2][64][64];
    __shared__ alignas(16) __fp16 sVT[2][4][68];

    const int id = blockIdx.x;
    const int sw = (id & 7) * 112 + (id >> 3);
    const int bt = sw >> 6;
    const int qblk = sw & 63;
    const int b = bt / 7, t = bt % 7;

    const int tid = threadIdx.x;
    const int lane = tid & 63;
    const int w = tid >> 6;
    const int col = lane & 15;
    const int g = lane >> 4;

    const int r = tid >> 2;
    const int c0 = (tid & 3) * 16;
    const int rs = (r & 7) << 3;
    const unsigned vr = (unsigned)tid / 3u;
    const unsigned vd = (unsigned)tid - vr * 3u;

    if (tid < 128) sVT[tid >> 6][3][tid & 63] = (__fp16)1.0f;

    const float* Qbase = K + (((size_t)b * 8 + (t + 1)) * 4096) * 64;
    h8 aq[2];
    {
        const int qrow = qblk * 64 + w * 16 + col;
        const float* qp = Qbase + (size_t)qrow * 64;
#pragma unroll
        for (int ch = 0; ch < 2; ++ch) {
            const int cc = ch * 32 + g * 8;
            const f32x4 xa = *(const f32x4*)&qp[cc];
            const f32x4 xb = *(const f32x4*)&qp[cc + 4];
            const h2 p0 = pkrtz(xa[0] * LOG2E, xa[1] * LOG2E);
            const h2 p1 = pkrtz(xa[2] * LOG2E, xa[3] * LOG2E);
            const h2 p2 = pkrtz(xb[0] * LOG2E, xb[1] * LOG2E);
            const h2 p3 = pkrtz(xb[2] * LOG2E, xb[3] * LOG2E);
            aq[ch] = (h8){p0[0], p0[1], p1[0], p1[1], p2[0], p2[1], p3[0], p3[1]};
        }
    }

    float outc0 = 0.f, outc1 = 0.f, outc2 = 0.f;

    for (int phase = 0; phase < 2; ++phase) {
        const float* kp; const float* vp; int ntile; float wgt;
        if (phase == 0) {
            kp = K + (((size_t)b * 8 + t) * 4096) * 64;
            vp = V + (((size_t)b * 8 + t) * 4096) * 3;
            ntile = 64; wgt = 0.8f;
        } else {
            kp = MK + (((size_t)b * 7 + t) * 1024) * 64;
            vp = MV + (((size_t)b * 7 + t) * 1024) * 3;
            ntile = 16; wgt = 0.2f;
        }
        {
            const float* src = kp + ((size_t)r) * 64 + c0;
            const f32x4* s4 = (const f32x4*)src;
            const f32x4 ra = s4[0], rb = s4[1], rc = s4[2], rd = s4[3];
            const h2 q0 = pkrtz(ra[0], ra[1]), q1 = pkrtz(ra[2], ra[3]);
            const h2 q2 = pkrtz(rb[0], rb[1]), q3 = pkrtz(rb[2], rb[3]);
            const h2 q4 = pkrtz(rc[0], rc[1]), q5 = pkrtz(rc[2], rc[3]);
            const h2 q6 = pkrtz(rd[0], rd[1]), q7 = pkrtz(rd[2], rd[3]);
            *(h8*)&sK[0][r][c0 ^ rs] = (h8){q0[0], q0[1], q1[0], q1[1], q2[0], q2[1], q3[0], q3[1]};
            *(h8*)&sK[0][r][(c0 + 8) ^ rs] = (h8){q4[0], q4[1], q5[0], q5[1], q6[0], q6[1], q7[0], q7[1]};
            if (tid < 192) sVT[0][vd][vr] = (__fp16)vp[tid];
        }
        __syncthreads();

        float mrun = -1e30f;
        f32x4 O = (f32x4){0.f, 0.f, 0.f, 0.f};

        for (int kt = 0; kt < ntile; ++kt) {
            const int cur = kt & 1;
            const bool have = (kt + 1) < ntile;
            f32x4 ra, rb, rc, rd; float rv = 0.f;
            if (have) {
                const float* src = kp + ((size_t)(kt + 1) * 64 + r) * 64 + c0;
                const f32x4* s4 = (const f32x4*)src;
                ra = s4[0]; rb = s4[1]; rc = s4[2]; rd = s4[3];
                if (tid < 192) rv = vp[(size_t)(kt + 1) * 192 + tid];
            }
            f32x4 acc[4];
#pragma unroll
            for (int nt = 0; nt < 4; ++nt) acc[nt] = (f32x4){0.f, 0.f, 0.f, 0.f};
#pragma unroll
            for (int ch = 0; ch < 2; ++ch) {
                h8 bh[4];
#pragma unroll
                for (int nt = 0; nt < 4; ++nt) {
                    const int rr = nt * 16 + col;
                    const int cc = (ch * 32 + g * 8) ^ ((rr & 7) << 3);
                    bh[nt] = *(const h8*)&sK[cur][rr][cc];
                }
#pragma unroll
                for (int nt = 0; nt < 4; ++nt)
                    acc[nt] = __builtin_amdgcn_mfma_f32_16x16x32_f16(bh[nt], aq[ch], acc[nt], 0, 0, 0);
            }
            {
                float tm = acc[0][0];
#pragma unroll
                for (int nt = 0; nt < 4; ++nt)
#pragma unroll
                    for (int j = 0; j < 4; ++j) tm = fmaxf(tm, acc[nt][j]);
                tm = fmaxf(tm, __shfl_xor(tm, 16));
                tm = fmaxf(tm, __shfl_xor(tm, 32));
                if (!__all(tm <= mrun)) {
                    const float mnew = fmaxf(mrun, tm);
                    const float sc = __builtin_amdgcn_exp2f(mrun - mnew);
                    O *= sc;
                    mrun = mnew;
                }
            }
#pragma unroll
            for (int nt = 0; nt < 4; ++nt) {
                const float p0 = __builtin_amdgcn_exp2f(acc[nt][0] - mrun);
                const float p1 = __builtin_amdgcn_exp2f(acc[nt][1] - mrun);
                const float p2 = __builtin_amdgcn_exp2f(acc[nt][2] - mrun);
                const float p3 = __builtin_amdgcn_exp2f(acc[nt][3] - mrun);
                const h2 pa = pkrtz(p0, p1), pb = pkrtz(p2, p3);
                const h4 pf = (h4){pa[0], pa[1], pb[0], pb[1]};
                const h4 vf = *(const h4*)&sVT[cur][col & 3][nt * 16 + 4 * g];
                O = __builtin_amdgcn_mfma_f32_16x16x16f16(vf, pf, O, 0, 0, 0);
            }
            if (have) {
                const int nb = cur ^ 1;
                const h2 q0 = pkrtz(ra[0], ra[1]), q1 = pkrtz(ra[2], ra[3]);
                const h2 q2 = pkrtz(rb[0], rb[1]), q3 = pkrtz(rb[2], rb[3]);
                const h2 q4 = pkrtz(rc[0], rc[1]), q5 = pkrtz(rc[2], rc[3]);
                const h2 q6 = pkrtz(rd[0], rd[1]), q7 = pkrtz(rd[2], rd[3]);
                *(h8*)&sK[nb][r][c0 ^ rs] = (h8){q0[0], q0[1], q1[0], q1[1], q2[0], q2[1], q3[0], q3[1]};
                *(h8*)&sK[nb][r][(c0 + 8) ^ rs] = (h8){q4[0], q4[1], q5[0], q5[1], q6[0], q6[1], q7[0], q7[1]};
                if (tid < 192) sVT[nb][vd][vr] = (__fp16)rv;
            }
            __syncthreads();
        }
        const float inv = wgt / O[3];
        outc0 += O[0] * inv;
        outc1 += O[1] * inv;
        outc2 += O[2] * inv;
    }

    if (g == 0) {
        const int q = qblk * 64 + w * 16 + col;
        float* op = OUT + (((size_t)b * 7 + t) * 4096 + (size_t)q) * 3;
        op[0] = outc0; op[1] = outc1; op[2] = outc2;
    }
}

extern "C" void kernel_launch(void* const* d_in, const int* in_sizes, int n_in,
                              void* d_out, int out_size, void* d_ws, size_t ws_size,
                              hipStream_t stream) {
    const float* K  = (const float*)d_in[0];
    const float* V  = (const float*)d_in[1];
    const float* MK = (const float*)d_in[2];
    const float* MV = (const float*)d_in[3];
    float* OUT = (float*)d_out;
    if (ws_size >= WS_NEED) {
        hipLaunchKernelGGL(kast_pre_kernel, dim3(2520), dim3(256), 0, stream,
                           K, V, MK, MV, (char*)d_ws);
        hipLaunchKernelGGL(kast_attn_kernel, dim3(1792), dim3(256), 0, stream,
                           K, (const char*)d_ws, OUT);
    } else {
        hipLaunchKernelGGL(kast_attn_fb, dim3(896), dim3(256), 0, stream,
                           K, V, MK, MV, OUT);
    }
}